// Round 1
// baseline (8973.709 us; speedup 1.0000x reference)
//
#include <hip/hip_runtime.h>

// ============================================================================
// Transformer encoder forward, fp32 baseline (correctness-first).
// T=1024, D=1024, H=16, HD=64, DFF=4096, V=32000, L=6.
// Workspace layout (floats): needs ~113.5 MB of d_ws.
// ============================================================================

#define TD   1024   // context length
#define DD   1024   // emb dim
#define NH   16     // heads
#define HDIM 64     // head dim
#define FF   4096   // ffn dim
#define VOC  32000  // vocab
#define NL   6      // layers

// ---------------------------------------------------------------------------
// Embedding: X is one-hot (1,T,V) -> gather W_emb row + pos. One block per t.
// ---------------------------------------------------------------------------
__global__ __launch_bounds__(256) void embed_kernel(
    const float* __restrict__ X, const float* __restrict__ Wemb,
    const float* __restrict__ pos, float* __restrict__ Xe)
{
  const int t = blockIdx.x;
  __shared__ int sidx;
  const float* row = X + (size_t)t * VOC;
  for (int i = threadIdx.x; i < VOC; i += 256)
    if (row[i] > 0.5f) sidx = i;   // exactly one 1.0 per row
  __syncthreads();
  const float* w = Wemb + (size_t)sidx * DD;
  const float* p = pos + (size_t)t * DD;
  float* o = Xe + (size_t)t * DD;
  for (int d = threadIdx.x; d < DD; d += 256)
    o[d] = w[d] + p[d];
}

// ---------------------------------------------------------------------------
// LayerNorm over the SEQUENCE axis (per column d, over t=0..T-1, ddof=1).
// Two kernels: column partial stats, then reduce+apply.
// part layout: part[col*64 + tc] = sum, part[col*64 + 32 + tc] = sumsq
// ---------------------------------------------------------------------------
__global__ __launch_bounds__(256) void ln_stats_kernel(
    const float* __restrict__ Y, float* __restrict__ part)
{
  const int col = blockIdx.x * 256 + threadIdx.x;  // gridDim.x = 4
  const int tc  = blockIdx.y;                      // gridDim.y = 32 (32 rows each)
  const float* p = Y + (size_t)(tc * 32) * DD + col;
  float s = 0.f, s2 = 0.f;
  #pragma unroll 8
  for (int t = 0; t < 32; ++t) {
    float v = p[(size_t)t * DD];
    s += v;
    s2 = fmaf(v, v, s2);
  }
  part[col * 64 + tc]      = s;
  part[col * 64 + 32 + tc] = s2;
}

__global__ __launch_bounds__(256) void ln_apply_kernel(
    const float* __restrict__ Y, const float* __restrict__ part,
    const float* __restrict__ g, const float* __restrict__ b,
    float* __restrict__ out)
{
  const int col = blockIdx.x * 256 + threadIdx.x;
  const int tc  = blockIdx.y;
  float s = 0.f, s2 = 0.f;
  const float* pp = part + col * 64;
  #pragma unroll
  for (int i = 0; i < 32; ++i) { s += pp[i]; s2 += pp[32 + i]; }
  const float mu  = s * (1.0f / TD);
  const float var = (s2 - (float)TD * mu * mu) * (1.0f / (TD - 1));
  const float inv = 1.0f / sqrtf(var);
  const float gi  = g[col] * inv;
  const float bb  = b[col];
  const float* yp = Y   + (size_t)(tc * 32) * DD + col;
  float*       op = out + (size_t)(tc * 32) * DD + col;
  #pragma unroll 8
  for (int t = 0; t < 32; ++t)
    op[(size_t)t * DD] = fmaf(gi, yp[(size_t)t * DD] - mu, bb);
}

// ---------------------------------------------------------------------------
// Row softmax over last dim (row length = TD = 1024). One block per row.
// ---------------------------------------------------------------------------
__global__ __launch_bounds__(256) void softmax_kernel(float* __restrict__ Z)
{
  const size_t row = blockIdx.x;
  float4* p = (float4*)(Z + row * TD);
  const int tid = threadIdx.x;
  float4 v = p[tid];

  float m = fmaxf(fmaxf(v.x, v.y), fmaxf(v.z, v.w));
  #pragma unroll
  for (int o = 32; o; o >>= 1) m = fmaxf(m, __shfl_xor(m, o, 64));
  __shared__ float redm[4];
  if ((tid & 63) == 0) redm[tid >> 6] = m;
  __syncthreads();
  m = fmaxf(fmaxf(redm[0], redm[1]), fmaxf(redm[2], redm[3]));

  v.x = expf(v.x - m); v.y = expf(v.y - m);
  v.z = expf(v.z - m); v.w = expf(v.w - m);
  float s = v.x + v.y + v.z + v.w;
  #pragma unroll
  for (int o = 32; o; o >>= 1) s += __shfl_xor(s, o, 64);
  __shared__ float reds[4];
  if ((tid & 63) == 0) reds[tid >> 6] = s;
  __syncthreads();
  s = reds[0] + reds[1] + reds[2] + reds[3];

  const float r = 1.0f / s;
  v.x *= r; v.y *= r; v.z *= r; v.w *= r;
  p[tid] = v;
}

// ---------------------------------------------------------------------------
// Generic tiled fp32 GEMM, batched via blockIdx.z with element strides.
//   C[row,col] = alpha * sum_k A[row,k] * B(k,col)  (+ bias[col]) (+ R[row,col]) (relu)
// BMODE 0: B[k*ldb + col]   (B stored K x N)
// BMODE 1: B[col*ldb + k]   (B stored N x K, i.e. torch Linear weight)
// All of M,N,K must be multiples of the tile dims (true for this model).
// ---------------------------------------------------------------------------
template<int BM, int BN, int BK, int TM, int TN, int BMODE,
         bool BIAS, bool RESID, bool RELU>
__global__ __launch_bounds__(256) void gemm_f32(
    const float* __restrict__ A, const float* __restrict__ B,
    const float* __restrict__ bias, const float* __restrict__ R,
    float* __restrict__ C,
    int M, int N, int K, int lda, int ldb, int ldc,
    long long sAz, long long sBz, long long sCz, long long sRz,
    float alpha)
{
  constexpr int NT = (BM / TM) * (BN / TN);
  static_assert(NT == 256, "block must be 256 threads");
  __shared__ float As[BK][BM + 4];
  __shared__ float Bs[BK][BN + 4];

  const int z = blockIdx.z;
  A += (size_t)z * sAz;
  B += (size_t)z * sBz;
  C += (size_t)z * sCz;
  if (RESID) R += (size_t)z * sRz;

  const int bm = blockIdx.x * BM;
  const int bn = blockIdx.y * BN;
  const int tid = threadIdx.x;
  const int tx = tid % (BN / TN);
  const int ty = tid / (BN / TN);

  float acc[TM][TN] = {};

  for (int k0 = 0; k0 < K; k0 += BK) {
    #pragma unroll
    for (int i = tid; i < BM * BK; i += NT) {
      const int m = i / BK, kk = i % BK;
      As[kk][m] = A[(size_t)(bm + m) * lda + (k0 + kk)];
    }
    #pragma unroll
    for (int i = tid; i < BK * BN; i += NT) {
      if constexpr (BMODE == 0) {
        const int kk = i / BN, n = i % BN;
        Bs[kk][n] = B[(size_t)(k0 + kk) * ldb + (bn + n)];
      } else {
        const int n = i / BK, kk = i % BK;
        Bs[kk][n] = B[(size_t)(bn + n) * ldb + (k0 + kk)];
      }
    }
    __syncthreads();

    #pragma unroll
    for (int kk = 0; kk < BK; ++kk) {
      float a[TM], b[TN];
      #pragma unroll
      for (int i = 0; i < TM; ++i) a[i] = As[kk][ty * TM + i];
      #pragma unroll
      for (int j = 0; j < TN; ++j) b[j] = Bs[kk][tx * TN + j];
      #pragma unroll
      for (int i = 0; i < TM; ++i)
        #pragma unroll
        for (int j = 0; j < TN; ++j)
          acc[i][j] = fmaf(a[i], b[j], acc[i][j]);
    }
    __syncthreads();
  }

  #pragma unroll
  for (int i = 0; i < TM; ++i) {
    const size_t row = bm + ty * TM + i;
    #pragma unroll
    for (int j = 0; j < TN; ++j) {
      const int col = bn + tx * TN + j;
      float v = acc[i][j] * alpha;
      if constexpr (BIAS)  v += bias[col];
      if constexpr (RESID) v += R[row * ldc + col];
      if constexpr (RELU)  v = fmaxf(v, 0.0f);
      C[row * ldc + col] = v;
    }
  }
}

// ---------------------------------------------------------------------------
// Host launcher
// ---------------------------------------------------------------------------
extern "C" void kernel_launch(void* const* d_in, const int* in_sizes, int n_in,
                              void* d_out, int out_size, void* d_ws, size_t ws_size,
                              hipStream_t stream)
{
  const float* X     = (const float*)d_in[0];
  const float* Wemb  = (const float*)d_in[1];
  const float* pos   = (const float*)d_in[2];
  const float* WQ    = (const float*)d_in[3];
  const float* WK    = (const float*)d_in[4];
  const float* WV    = (const float*)d_in[5];
  const float* Wout  = (const float*)d_in[6];
  const float* ln1g  = (const float*)d_in[7];
  const float* ln1b  = (const float*)d_in[8];
  const float* ln2g  = (const float*)d_in[9];
  const float* ln2b  = (const float*)d_in[10];
  const float* w1    = (const float*)d_in[11];
  const float* b1    = (const float*)d_in[12];
  const float* w2    = (const float*)d_in[13];
  const float* b2    = (const float*)d_in[14];
  const float* lastg = (const float*)d_in[15];
  const float* lastb = (const float*)d_in[16];
  float* out = (float*)d_out;

  // workspace carve-up (floats); total = 28,377,088 floats ~= 113.5 MB
  float* ws   = (float*)d_ws;
  float* XE   = ws;                  // 1M  residual stream
  float* Yb   = XE + (1 << 20);      // 1M  post-attention residual
  float* LN   = Yb + (1 << 20);      // 1M  layernorm output
  float* Qb   = LN + (1 << 20);      // 1M  Q, layout (t, n*64+h)
  float* Kb   = Qb + (1 << 20);      // 1M
  float* Vb   = Kb + (1 << 20);      // 1M
  float* XO   = Vb + (1 << 20);      // 1M  attn output, heads concatenated
  float* Hb   = XO + (1 << 20);      // 4M  ffn hidden (t, 4096)
  float* Zb   = Hb + (4 << 20);      // 16M attention scores (n, t, s)
  float* part = Zb + (16 << 20);     // 64K LN partials

  // ---- embedding ----
  embed_kernel<<<TD, 256, 0, stream>>>(X, Wemb, pos, XE);

  for (int l = 0; l < NL; ++l) {
    const float* WQl = WQ   + (size_t)l * NH * DD * HDIM;
    const float* WKl = WK   + (size_t)l * NH * DD * HDIM;
    const float* WVl = WV   + (size_t)l * NH * DD * HDIM;
    const float* WOl = Wout + (size_t)l * DD * DD;
    const float* w1l = w1 + (size_t)l * FF * DD;
    const float* b1l = b1 + (size_t)l * FF;
    const float* w2l = w2 + (size_t)l * DD * FF;
    const float* b2l = b2 + (size_t)l * DD;

    // ---- LN1 (over sequence axis) ----
    ln_stats_kernel<<<dim3(4, 32), 256, 0, stream>>>(XE, part);
    ln_apply_kernel<<<dim3(4, 32), 256, 0, stream>>>(XE, part, ln1g + l * DD, ln1b + l * DD, LN);

    // ---- QKV projections: per head z, (1024x1024)x(1024x64) ----
    gemm_f32<64, 64, 16, 4, 4, 0, false, false, false><<<dim3(16, 1, NH), 256, 0, stream>>>(
        LN, WQl, nullptr, nullptr, Qb, TD, HDIM, DD, DD, HDIM, DD,
        0LL, (long long)DD * HDIM, (long long)HDIM, 0LL, 1.0f);
    gemm_f32<64, 64, 16, 4, 4, 0, false, false, false><<<dim3(16, 1, NH), 256, 0, stream>>>(
        LN, WKl, nullptr, nullptr, Kb, TD, HDIM, DD, DD, HDIM, DD,
        0LL, (long long)DD * HDIM, (long long)HDIM, 0LL, 1.0f);
    gemm_f32<64, 64, 16, 4, 4, 0, false, false, false><<<dim3(16, 1, NH), 256, 0, stream>>>(
        LN, WVl, nullptr, nullptr, Vb, TD, HDIM, DD, DD, HDIM, DD,
        0LL, (long long)DD * HDIM, (long long)HDIM, 0LL, 1.0f);

    // ---- Z = Q K^T / 8, per head ----
    gemm_f32<128, 128, 16, 8, 8, 1, false, false, false><<<dim3(8, 8, NH), 256, 0, stream>>>(
        Qb, Kb, nullptr, nullptr, Zb, TD, TD, HDIM, DD, DD, TD,
        (long long)HDIM, (long long)HDIM, (long long)TD * TD, 0LL, 0.125f);

    // ---- softmax rows ----
    softmax_kernel<<<NH * TD, 256, 0, stream>>>(Zb);

    // ---- XO = A V, written directly into concatenated-head layout ----
    gemm_f32<64, 64, 16, 4, 4, 0, false, false, false><<<dim3(16, 1, NH), 256, 0, stream>>>(
        Zb, Vb, nullptr, nullptr, XO, TD, HDIM, TD, TD, DD, DD,
        (long long)TD * TD, (long long)HDIM, (long long)HDIM, 0LL, 1.0f);

    // ---- Y = XE + XO @ Wout ----
    gemm_f32<64, 64, 16, 4, 4, 0, false, true, false><<<dim3(16, 16, 1), 256, 0, stream>>>(
        XO, WOl, nullptr, XE, Yb, TD, DD, DD, DD, DD, DD,
        0LL, 0LL, 0LL, 0LL, 1.0f);

    // ---- LN2 ----
    ln_stats_kernel<<<dim3(4, 32), 256, 0, stream>>>(Yb, part);
    ln_apply_kernel<<<dim3(4, 32), 256, 0, stream>>>(Yb, part, ln2g + l * DD, ln2b + l * DD, LN);

    // ---- FFN1: H = relu(LN @ w1^T + b1) ----
    gemm_f32<64, 64, 16, 4, 4, 1, true, false, true><<<dim3(16, 64, 1), 256, 0, stream>>>(
        LN, w1l, b1l, nullptr, Hb, TD, FF, DD, DD, DD, FF,
        0LL, 0LL, 0LL, 0LL, 1.0f);

    // ---- FFN2: XE = Yb + H @ w2^T + b2 ----
    gemm_f32<64, 64, 16, 4, 4, 1, true, true, false><<<dim3(16, 16, 1), 256, 0, stream>>>(
        Hb, w2l, b2l, Yb, XE, TD, DD, FF, FF, FF, DD,
        0LL, 0LL, 0LL, 0LL, 1.0f);
  }

  // ---- final LN -> d_out ----
  ln_stats_kernel<<<dim3(4, 32), 256, 0, stream>>>(XE, part);
  ln_apply_kernel<<<dim3(4, 32), 256, 0, stream>>>(XE, part, lastg, lastb, out);
}

// Round 2
// 1881.475 us; speedup vs baseline: 4.7695x; 4.7695x over previous
//
#include <hip/hip_runtime.h>

// ============================================================================
// Transformer encoder forward — bf16 MFMA GEMMs, fp32 residual/LN/softmax.
// T=1024, D=1024, H=16, HD=64, DFF=4096, V=32000, L=6.  ws use ~105 MB.
// ============================================================================

#define TD   1024
#define DD   1024
#define NH   16
#define HDIM 64
#define FF   4096
#define VOC  32000
#define NL   6

typedef __bf16 bf16;
typedef __bf16 bf16x4 __attribute__((ext_vector_type(4)));
typedef __bf16 bf16x8 __attribute__((ext_vector_type(8)));
typedef float  f32x4  __attribute__((ext_vector_type(4)));

// async global->LDS, 16B per lane; dest = wave-uniform base + lane*16
__device__ __forceinline__ void gload_lds16(const void* g, void* l) {
  __builtin_amdgcn_global_load_lds(
      (__attribute__((address_space(1))) void*)(g),
      (__attribute__((address_space(3))) void*)(l), 16, 0, 0);
}

// ---------------------------------------------------------------------------
// Embedding: one-hot gather + positional add. One block per t.
// ---------------------------------------------------------------------------
__global__ __launch_bounds__(256) void embed_kernel(
    const float* __restrict__ X, const float* __restrict__ Wemb,
    const float* __restrict__ pos, float* __restrict__ Xe)
{
  const int t = blockIdx.x;
  __shared__ int sidx;
  const float4* row = (const float4*)(X + (size_t)t * VOC);
  for (int i = threadIdx.x; i < VOC / 4; i += 256) {
    float4 v = row[i];
    if (v.x > 0.5f) sidx = 4 * i;
    if (v.y > 0.5f) sidx = 4 * i + 1;
    if (v.z > 0.5f) sidx = 4 * i + 2;
    if (v.w > 0.5f) sidx = 4 * i + 3;
  }
  __syncthreads();
  const float4* w = (const float4*)(Wemb + (size_t)sidx * DD);
  const float4* p = (const float4*)(pos + (size_t)t * DD);
  float4* o = (float4*)(Xe + (size_t)t * DD);
  const int d = threadIdx.x;   // 256 threads x float4 = 1024
  float4 a = w[d], b = p[d];
  o[d] = make_float4(a.x + b.x, a.y + b.y, a.z + b.z, a.w + b.w);
}

// ---------------------------------------------------------------------------
// LayerNorm over the SEQUENCE axis (per column d, over t, ddof=1).
// ---------------------------------------------------------------------------
__global__ __launch_bounds__(256) void ln_stats_kernel(
    const float* __restrict__ Y, float* __restrict__ part)
{
  const int col = blockIdx.x * 256 + threadIdx.x;
  const int tc  = blockIdx.y;
  const float* p = Y + (size_t)(tc * 32) * DD + col;
  float s = 0.f, s2 = 0.f;
  #pragma unroll 8
  for (int t = 0; t < 32; ++t) {
    float v = p[(size_t)t * DD];
    s += v;
    s2 = fmaf(v, v, s2);
  }
  part[col * 64 + tc]      = s;
  part[col * 64 + 32 + tc] = s2;
}

template<typename OutT>
__global__ __launch_bounds__(256) void ln_apply_kernel(
    const float* __restrict__ Y, const float* __restrict__ part,
    const float* __restrict__ g, const float* __restrict__ b,
    OutT* __restrict__ out)
{
  const int col = blockIdx.x * 256 + threadIdx.x;
  const int tc  = blockIdx.y;
  float s = 0.f, s2 = 0.f;
  const float* pp = part + col * 64;
  #pragma unroll
  for (int i = 0; i < 32; ++i) { s += pp[i]; s2 += pp[32 + i]; }
  const float mu  = s * (1.0f / TD);
  const float var = (s2 - (float)TD * mu * mu) * (1.0f / (TD - 1));
  const float inv = 1.0f / sqrtf(var);
  const float gi  = g[col] * inv;
  const float bb  = b[col];
  const float* yp = Y   + (size_t)(tc * 32) * DD + col;
  OutT*        op = out + (size_t)(tc * 32) * DD + col;
  #pragma unroll 8
  for (int t = 0; t < 32; ++t)
    op[(size_t)t * DD] = (OutT)fmaf(gi, yp[(size_t)t * DD] - mu, bb);
}

// ---------------------------------------------------------------------------
// Row softmax: fp32 in, bf16 out. One block per row of 1024.
// ---------------------------------------------------------------------------
__global__ __launch_bounds__(256) void softmax_bf(
    const float* __restrict__ Z, bf16* __restrict__ A)
{
  const size_t row = blockIdx.x;
  const float4* p = (const float4*)(Z + row * TD);
  const int tid = threadIdx.x;
  float4 v = p[tid];

  float m = fmaxf(fmaxf(v.x, v.y), fmaxf(v.z, v.w));
  #pragma unroll
  for (int o = 32; o; o >>= 1) m = fmaxf(m, __shfl_xor(m, o, 64));
  __shared__ float redm[4];
  if ((tid & 63) == 0) redm[tid >> 6] = m;
  __syncthreads();
  m = fmaxf(fmaxf(redm[0], redm[1]), fmaxf(redm[2], redm[3]));

  v.x = __expf(v.x - m); v.y = __expf(v.y - m);
  v.z = __expf(v.z - m); v.w = __expf(v.w - m);
  float s = v.x + v.y + v.z + v.w;
  #pragma unroll
  for (int o = 32; o; o >>= 1) s += __shfl_xor(s, o, 64);
  __shared__ float reds[4];
  if ((tid & 63) == 0) reds[tid >> 6] = s;
  __syncthreads();
  s = reds[0] + reds[1] + reds[2] + reds[3];

  const float r = 1.0f / s;
  bf16x4 o4 = { (bf16)(v.x * r), (bf16)(v.y * r), (bf16)(v.z * r), (bf16)(v.w * r) };
  *(bf16x4*)(A + row * TD + tid * 4) = o4;
}

// ---------------------------------------------------------------------------
// 64x64 tile transpose + cast to bf16 (ST = float or bf16).
// dst[r][c] (tile at by,bx) = src[c][r] (tile at bx,by)
// ---------------------------------------------------------------------------
template<typename ST>
__global__ __launch_bounds__(256) void transpose_cast(
    const ST* __restrict__ src, int lds_, long long sZ,
    bf16* __restrict__ dst, int ldd, long long dZ)
{
  __shared__ ST tile[64][65];
  src += (size_t)blockIdx.z * sZ + (size_t)(blockIdx.x * 64) * lds_ + blockIdx.y * 64;
  dst += (size_t)blockIdx.z * dZ + (size_t)(blockIdx.y * 64) * ldd + blockIdx.x * 64;
  const int tid = threadIdx.x;
  #pragma unroll
  for (int k = 0; k < 16; ++k) {
    const int idx = tid + k * 256;
    const int r = idx >> 6, c = idx & 63;
    tile[r][c] = src[(size_t)r * lds_ + c];
  }
  __syncthreads();
  #pragma unroll
  for (int k = 0; k < 16; ++k) {
    const int idx = tid + k * 256;
    const int r = idx >> 6, c = idx & 63;
    dst[(size_t)r * ldd + c] = (bf16)(float)tile[c][r];
  }
}

// straight fp32 -> bf16 cast, 4 elems/thread
__global__ __launch_bounds__(256) void cast_bf4(
    const float* __restrict__ s, bf16* __restrict__ d, int n4)
{
  const int i = blockIdx.x * 256 + threadIdx.x;
  if (i < n4) {
    float4 v = ((const float4*)s)[i];
    bf16x4 o = { (bf16)v.x, (bf16)v.y, (bf16)v.z, (bf16)v.w };
    ((bf16x4*)d)[i] = o;
  }
}

// ---------------------------------------------------------------------------
// bf16 MFMA GEMM (m97 structure): C = alpha * A(MxK) * B(NxK)^T [+bias][+R][relu]
// A row-major (lda), B row-major N x K (ldb), C row-major (ldc), batch via z.
// BK = 64. Tiles: BM x BN, 4 waves in WGM x WGN grid.
// ---------------------------------------------------------------------------
template<int BM, int BN, int WGM, int WGN, bool OUTBF, bool BIAS, bool RESID, bool RELU>
__global__ __launch_bounds__(256) void gemm_bf16(
    const bf16* __restrict__ A, const bf16* __restrict__ B,
    const float* __restrict__ bias, const float* __restrict__ R,
    void* __restrict__ Cv,
    int K, int lda, int ldb, int ldc,
    long long sA, long long sB, long long sC, float alpha)
{
  constexpr int FM = BM / WGM / 16;
  constexpr int FN = BN / WGN / 16;
  __shared__ bf16 sm[(BM + BN) * 64];
  bf16* As = sm;
  bf16* Bs = sm + BM * 64;

  const int z = blockIdx.z;
  A += (size_t)z * sA + (size_t)(blockIdx.x * BM) * lda;
  B += (size_t)z * sB + (size_t)(blockIdx.y * BN) * ldb;

  const int tid  = threadIdx.x;
  const int lane = tid & 63;
  const int wv   = tid >> 6;
  const int lr   = lane >> 3;          // row within 8-row segment
  const int lk   = (lane & 7) * 8;     // k element offset within row
  const int wr   = (wv / WGN) * FM * 16;
  const int wc   = (wv % WGN) * FN * 16;
  const int l15  = lane & 15;
  const int l16  = lane >> 4;

  f32x4 acc[FM][FN] = {};

  for (int k0 = 0; k0 < K; k0 += 64) {
    #pragma unroll
    for (int s8 = 0; s8 < BM / 32; ++s8) {
      const int s = s8 * 4 + wv;
      gload_lds16(A + (size_t)(s * 8 + lr) * lda + (k0 + lk), As + s * 512);
    }
    #pragma unroll
    for (int s8 = 0; s8 < BN / 32; ++s8) {
      const int s = s8 * 4 + wv;
      gload_lds16(B + (size_t)(s * 8 + lr) * ldb + (k0 + lk), Bs + s * 512);
    }
    __syncthreads();

    #pragma unroll
    for (int ks = 0; ks < 2; ++ks) {
      const int ko = ks * 32 + l16 * 8;
      bf16x8 af[FM], bg[FN];
      #pragma unroll
      for (int i = 0; i < FM; ++i)
        af[i] = *(const bf16x8*)(As + (wr + i * 16 + l15) * 64 + ko);
      #pragma unroll
      for (int j = 0; j < FN; ++j)
        bg[j] = *(const bf16x8*)(Bs + (wc + j * 16 + l15) * 64 + ko);
      #pragma unroll
      for (int i = 0; i < FM; ++i)
        #pragma unroll
        for (int j = 0; j < FN; ++j)
          acc[i][j] = __builtin_amdgcn_mfma_f32_16x16x32_bf16(af[i], bg[j], acc[i][j], 0, 0, 0);
    }
    __syncthreads();
  }

  // epilogue: C/D frag layout col = lane&15, row = (lane>>4)*4 + reg
  const int brow = blockIdx.x * BM;
  const int bcol = blockIdx.y * BN;
  float* Cf = (float*)Cv;
  bf16*  Cb = (bf16*)Cv;
  #pragma unroll
  for (int i = 0; i < FM; ++i) {
    const int r0 = brow + wr + i * 16 + l16 * 4;
    #pragma unroll
    for (int j = 0; j < FN; ++j) {
      const int c = bcol + wc + j * 16 + l15;
      float bsv = 0.f;
      if constexpr (BIAS) bsv = bias[c];
      #pragma unroll
      for (int r = 0; r < 4; ++r) {
        float v = acc[i][j][r] * alpha + bsv;
        if constexpr (RESID) v += R[(size_t)(r0 + r) * ldc + c];
        if constexpr (RELU)  v = fmaxf(v, 0.f);
        const size_t off = (size_t)z * sC + (size_t)(r0 + r) * ldc + c;
        if constexpr (OUTBF) Cb[off] = (bf16)v; else Cf[off] = v;
      }
    }
  }
}

// ---------------------------------------------------------------------------
// Host launcher
// ---------------------------------------------------------------------------
extern "C" void kernel_launch(void* const* d_in, const int* in_sizes, int n_in,
                              void* d_out, int out_size, void* d_ws, size_t ws_size,
                              hipStream_t stream)
{
  const float* X     = (const float*)d_in[0];
  const float* Wemb  = (const float*)d_in[1];
  const float* pos   = (const float*)d_in[2];
  const float* WQ    = (const float*)d_in[3];
  const float* WK    = (const float*)d_in[4];
  const float* WV    = (const float*)d_in[5];
  const float* Wout  = (const float*)d_in[6];
  const float* ln1g  = (const float*)d_in[7];
  const float* ln1b  = (const float*)d_in[8];
  const float* ln2g  = (const float*)d_in[9];
  const float* ln2b  = (const float*)d_in[10];
  const float* w1    = (const float*)d_in[11];
  const float* b1    = (const float*)d_in[12];
  const float* w2    = (const float*)d_in[13];
  const float* b2    = (const float*)d_in[14];
  const float* lastg = (const float*)d_in[15];
  const float* lastb = (const float*)d_in[16];
  float* out = (float*)d_out;

  // ---- workspace carve-up (byte offsets; total ~105.1 MB) ----
  char* w = (char*)d_ws;
  float* XE    = (float*)(w + 0);          // 4 MB fp32 residual
  float* Yb    = (float*)(w + 4194304);    // 4 MB fp32 post-attn residual
  float* part  = (float*)(w + 8388608);    // 256 KB LN partials
  bf16*  LNbf  = (bf16*)(w + 8650752);     // 2 MB   LN output (bf16)
  bf16*  QKVb  = (bf16*)(w + 10747904);    // 6 MB   QKV activations (t, 3072)
  bf16*  Vt    = (bf16*)(w + 17039360);    // 2 MB   V transposed (h*64+j, t)
  bf16*  XO    = (bf16*)(w + 19136512);    // 2 MB   attn out (t, d)
  bf16*  Hb    = (bf16*)(w + 21233664);    // 8 MB   ffn hidden (t, 4096)
  bf16*  QKVw  = (bf16*)(w + 29622272);    // 6 MB   packed QKV weights (3072, 1024)
  bf16*  WoutP = (bf16*)(w + 35913728);    // 2 MB   Wout^T (out, in)
  bf16*  w1b   = (bf16*)(w + 38010880);    // 8 MB   w1 cast (4096, 1024)
  bf16*  w2b   = (bf16*)(w + 46399488);    // 8 MB   w2 cast (1024, 4096)
  float* Zb    = (float*)(w + 54788096);   // 32 MB  scores, 8 heads fp32
  bf16*  Ab    = (bf16*)(w + 88342528);    // 16 MB  softmax probs, 8 heads bf16

  embed_kernel<<<TD, 256, 0, stream>>>(X, Wemb, pos, XE);

  for (int l = 0; l < NL; ++l) {
    const float* WQl = WQ   + (size_t)l * NH * DD * HDIM;
    const float* WKl = WK   + (size_t)l * NH * DD * HDIM;
    const float* WVl = WV   + (size_t)l * NH * DD * HDIM;
    const float* WOl = Wout + (size_t)l * DD * DD;
    const float* w1l = w1 + (size_t)l * FF * DD;
    const float* b1l = b1 + (size_t)l * FF;
    const float* w2l = w2 + (size_t)l * DD * FF;
    const float* b2l = b2 + (size_t)l * DD;

    // ---- pack weights for this layer (transpose-cast to (N,K) bf16) ----
    // WQ/WK/WV (16,1024,64) -> QKVw rows q*1024 + h*64 + j, cols d
    transpose_cast<float><<<dim3(16, 1, 16), 256, 0, stream>>>(
        WQl, HDIM, (long long)DD * HDIM, QKVw + 0 * (1 << 20), DD, (long long)HDIM * DD);
    transpose_cast<float><<<dim3(16, 1, 16), 256, 0, stream>>>(
        WKl, HDIM, (long long)DD * HDIM, QKVw + 1 * (1 << 20), DD, (long long)HDIM * DD);
    transpose_cast<float><<<dim3(16, 1, 16), 256, 0, stream>>>(
        WVl, HDIM, (long long)DD * HDIM, QKVw + 2 * (1 << 20), DD, (long long)HDIM * DD);
    // Wout (in,out) -> WoutP (out,in)
    transpose_cast<float><<<dim3(16, 16, 1), 256, 0, stream>>>(
        WOl, DD, 0LL, WoutP, DD, 0LL);
    // w1 (4096,1024) and w2 (1024,4096) are already (N,K): cast only
    cast_bf4<<<FF * DD / 4 / 256, 256, 0, stream>>>(w1l, w1b, FF * DD / 4);
    cast_bf4<<<FF * DD / 4 / 256, 256, 0, stream>>>(w2l, w2b, FF * DD / 4);

    // ---- LN1 -> bf16 ----
    ln_stats_kernel<<<dim3(4, 32), 256, 0, stream>>>(XE, part);
    ln_apply_kernel<bf16><<<dim3(4, 32), 256, 0, stream>>>(
        XE, part, ln1g + l * DD, ln1b + l * DD, LNbf);

    // ---- QKV: (1024x1024) x (3072x1024)^T -> QKVb bf16 (t, 3072) ----
    gemm_bf16<128, 128, 2, 2, true, false, false, false><<<dim3(8, 24, 1), 256, 0, stream>>>(
        LNbf, QKVw, nullptr, nullptr, QKVb, DD, DD, DD, 3 * DD, 0, 0, 0, 1.0f);

    // ---- V transpose: Vt[h*64+j][t] = QKVb[t][2048 + h*64+j] ----
    transpose_cast<bf16><<<dim3(16, 16, 1), 256, 0, stream>>>(
        QKVb + 2048, 3 * DD, 0LL, Vt, TD, 0LL);

    // ---- attention in 2 chunks of 8 heads ----
    for (int c = 0; c < 2; ++c) {
      // Z = Q K^T / 8 : A=Q section (lda 3072), B=K section as (s, j) rows
      gemm_bf16<128, 128, 2, 2, false, false, false, false><<<dim3(8, 8, 8), 256, 0, stream>>>(
          QKVb + c * 512, QKVb + DD + c * 512, nullptr, nullptr, Zb,
          HDIM, 3 * DD, 3 * DD, TD, 64, 64, 1 << 20, 0.125f);
      softmax_bf<<<8 * TD, 256, 0, stream>>>(Zb, Ab);
      // XO section = A V : B = Vt rows h*64.. (N=64, K=1024)
      gemm_bf16<128, 64, 4, 1, true, false, false, false><<<dim3(8, 1, 8), 256, 0, stream>>>(
          Ab, Vt + (size_t)c * 8 * HDIM * TD, nullptr, nullptr, XO + c * 512,
          TD, TD, TD, DD, 1 << 20, (long long)HDIM * TD, 64, 1.0f);
    }

    // ---- Y = XE + XO @ Wout ----
    gemm_bf16<64, 128, 2, 2, false, false, true, false><<<dim3(16, 8, 1), 256, 0, stream>>>(
        XO, WoutP, nullptr, XE, Yb, DD, DD, DD, DD, 0, 0, 0, 1.0f);

    // ---- LN2 -> bf16 ----
    ln_stats_kernel<<<dim3(4, 32), 256, 0, stream>>>(Yb, part);
    ln_apply_kernel<bf16><<<dim3(4, 32), 256, 0, stream>>>(
        Yb, part, ln2g + l * DD, ln2b + l * DD, LNbf);

    // ---- FFN1: H = relu(LN @ w1^T + b1) -> bf16 ----
    gemm_bf16<128, 128, 2, 2, true, true, false, true><<<dim3(8, 32, 1), 256, 0, stream>>>(
        LNbf, w1b, b1l, nullptr, Hb, DD, DD, DD, FF, 0, 0, 0, 1.0f);

    // ---- FFN2: XE = Yb + H @ w2^T + b2 ----
    gemm_bf16<64, 128, 2, 2, false, true, true, false><<<dim3(16, 8, 1), 256, 0, stream>>>(
        Hb, w2b, b2l, Yb, XE, FF, FF, FF, DD, 0, 0, 0, 1.0f);
  }

  // ---- final LN (fp32 out) ----
  ln_stats_kernel<<<dim3(4, 32), 256, 0, stream>>>(XE, part);
  ln_apply_kernel<float><<<dim3(4, 32), 256, 0, stream>>>(XE, part, lastg, lastb, out);
}

// Round 5
// 1464.595 us; speedup vs baseline: 6.1271x; 1.2846x over previous
//
#include <hip/hip_runtime.h>

// ============================================================================
// Transformer encoder forward — bf16 MFMA GEMMs + fused flash attention.
// T=1024, D=1024, H=16, HD=64, DFF=4096, V=32000, L=6.  ws use ~92.3 MB.
// ============================================================================

#define TD   1024
#define DD   1024
#define NH   16
#define HDIM 64
#define FF   4096
#define VOC  32000
#define NL   6

typedef __bf16 bf16;
typedef __bf16 bf16x4 __attribute__((ext_vector_type(4)));
typedef __bf16 bf16x8 __attribute__((ext_vector_type(8)));
typedef float  f32x4  __attribute__((ext_vector_type(4)));

// async global->LDS, 16B per lane; LDS dest = wave-uniform base + lane*16
__device__ __forceinline__ void gload_lds16(const void* g, void* l) {
  __builtin_amdgcn_global_load_lds(
      (__attribute__((address_space(1))) void*)(g),
      (__attribute__((address_space(3))) void*)(l), 16, 0, 0);
}

// ---------------------------------------------------------------------------
// Embedding: one-hot gather + positional add. One block per t.
// ---------------------------------------------------------------------------
__global__ __launch_bounds__(256) void embed_kernel(
    const float* __restrict__ X, const float* __restrict__ Wemb,
    const float* __restrict__ pos, float* __restrict__ Xe)
{
  const int t = blockIdx.x;
  __shared__ int sidx;
  const float4* row = (const float4*)(X + (size_t)t * VOC);
  for (int i = threadIdx.x; i < VOC / 4; i += 256) {
    float4 v = row[i];
    if (v.x > 0.5f) sidx = 4 * i;
    if (v.y > 0.5f) sidx = 4 * i + 1;
    if (v.z > 0.5f) sidx = 4 * i + 2;
    if (v.w > 0.5f) sidx = 4 * i + 3;
  }
  __syncthreads();
  const float4* w = (const float4*)(Wemb + (size_t)sidx * DD);
  const float4* p = (const float4*)(pos + (size_t)t * DD);
  float4* o = (float4*)(Xe + (size_t)t * DD);
  const int d = threadIdx.x;
  float4 a = w[d], b = p[d];
  o[d] = make_float4(a.x + b.x, a.y + b.y, a.z + b.z, a.w + b.w);
}

// ---------------------------------------------------------------------------
// LayerNorm over the SEQUENCE axis (per column d, over t, ddof=1).
// ---------------------------------------------------------------------------
__global__ __launch_bounds__(256) void ln_stats_kernel(
    const float* __restrict__ Y, float* __restrict__ part)
{
  const int col = blockIdx.x * 256 + threadIdx.x;
  const int tc  = blockIdx.y;
  const float* p = Y + (size_t)(tc * 32) * DD + col;
  float s = 0.f, s2 = 0.f;
  #pragma unroll 8
  for (int t = 0; t < 32; ++t) {
    float v = p[(size_t)t * DD];
    s += v;
    s2 = fmaf(v, v, s2);
  }
  part[col * 64 + tc]      = s;
  part[col * 64 + 32 + tc] = s2;
}

template<typename OutT>
__global__ __launch_bounds__(256) void ln_apply_kernel(
    const float* __restrict__ Y, const float* __restrict__ part,
    const float* __restrict__ g, const float* __restrict__ b,
    OutT* __restrict__ out)
{
  const int col = blockIdx.x * 256 + threadIdx.x;
  const int tc  = blockIdx.y;
  float s = 0.f, s2 = 0.f;
  const float* pp = part + col * 64;
  #pragma unroll
  for (int i = 0; i < 32; ++i) { s += pp[i]; s2 += pp[32 + i]; }
  const float mu  = s * (1.0f / TD);
  const float var = (s2 - (float)TD * mu * mu) * (1.0f / (TD - 1));
  const float inv = 1.0f / sqrtf(var);
  const float gi  = g[col] * inv;
  const float bb  = b[col];
  const float* yp = Y   + (size_t)(tc * 32) * DD + col;
  OutT*        op = out + (size_t)(tc * 32) * DD + col;
  #pragma unroll 8
  for (int t = 0; t < 32; ++t)
    op[(size_t)t * DD] = (OutT)fmaf(gi, yp[(size_t)t * DD] - mu, bb);
}

// ---------------------------------------------------------------------------
// 64x64 tile transpose + cast to bf16 (ST = float or bf16).
// dst tile (by,bx)[r][c] = src tile (bx,by)[c][r]
// ---------------------------------------------------------------------------
template<typename ST>
__global__ __launch_bounds__(256) void transpose_cast(
    const ST* __restrict__ src, int lds_, long long sZ,
    bf16* __restrict__ dst, int ldd, long long dZ)
{
  __shared__ ST tile[64][65];
  src += (size_t)blockIdx.z * sZ + (size_t)(blockIdx.x * 64) * lds_ + blockIdx.y * 64;
  dst += (size_t)blockIdx.z * dZ + (size_t)(blockIdx.y * 64) * ldd + blockIdx.x * 64;
  const int tid = threadIdx.x;
  #pragma unroll
  for (int k = 0; k < 16; ++k) {
    const int idx = tid + k * 256;
    const int r = idx >> 6, c = idx & 63;
    tile[r][c] = src[(size_t)r * lds_ + c];
  }
  __syncthreads();
  #pragma unroll
  for (int k = 0; k < 16; ++k) {
    const int idx = tid + k * 256;
    const int r = idx >> 6, c = idx & 63;
    dst[(size_t)r * ldd + c] = (bf16)(float)tile[c][r];
  }
}

// straight fp32 -> bf16 cast, 4 elems/thread
__global__ __launch_bounds__(256) void cast_bf4(
    const float* __restrict__ s, bf16* __restrict__ d, int n4)
{
  const int i = blockIdx.x * 256 + threadIdx.x;
  if (i < n4) {
    float4 v = ((const float4*)s)[i];
    bf16x4 o = { (bf16)v.x, (bf16)v.y, (bf16)v.z, (bf16)v.w };
    ((bf16x4*)d)[i] = o;
  }
}

// ---------------------------------------------------------------------------
// bf16 MFMA GEMM (m97 structure): C = alpha*A(MxK)*B(NxK)^T [+bias][+R][relu]
// ---------------------------------------------------------------------------
template<int BM, int BN, int WGM, int WGN, bool OUTBF, bool BIAS, bool RESID, bool RELU>
__global__ __launch_bounds__(256) void gemm_bf16(
    const bf16* __restrict__ A, const bf16* __restrict__ B,
    const float* __restrict__ bias, const float* __restrict__ R,
    void* __restrict__ Cv,
    int K, int lda, int ldb, int ldc,
    long long sA, long long sB, long long sC, float alpha)
{
  constexpr int FM = BM / WGM / 16;
  constexpr int FN = BN / WGN / 16;
  __shared__ bf16 sm[(BM + BN) * 64];
  bf16* As = sm;
  bf16* Bs = sm + BM * 64;

  const int z = blockIdx.z;
  A += (size_t)z * sA + (size_t)(blockIdx.x * BM) * lda;
  B += (size_t)z * sB + (size_t)(blockIdx.y * BN) * ldb;

  const int tid  = threadIdx.x;
  const int lane = tid & 63;
  const int wv   = tid >> 6;
  const int lr   = lane >> 3;
  const int lk   = (lane & 7) * 8;
  const int wr   = (wv / WGN) * FM * 16;
  const int wc   = (wv % WGN) * FN * 16;
  const int l15  = lane & 15;
  const int l16  = lane >> 4;

  f32x4 acc[FM][FN] = {};

  for (int k0 = 0; k0 < K; k0 += 64) {
    #pragma unroll
    for (int s8 = 0; s8 < BM / 32; ++s8) {
      const int s = s8 * 4 + wv;
      gload_lds16(A + (size_t)(s * 8 + lr) * lda + (k0 + lk), As + s * 512);
    }
    #pragma unroll
    for (int s8 = 0; s8 < BN / 32; ++s8) {
      const int s = s8 * 4 + wv;
      gload_lds16(B + (size_t)(s * 8 + lr) * ldb + (k0 + lk), Bs + s * 512);
    }
    __syncthreads();

    #pragma unroll
    for (int ks = 0; ks < 2; ++ks) {
      const int ko = ks * 32 + l16 * 8;
      bf16x8 af[FM], bg[FN];
      #pragma unroll
      for (int i = 0; i < FM; ++i)
        af[i] = *(const bf16x8*)(As + (wr + i * 16 + l15) * 64 + ko);
      #pragma unroll
      for (int j = 0; j < FN; ++j)
        bg[j] = *(const bf16x8*)(Bs + (wc + j * 16 + l15) * 64 + ko);
      #pragma unroll
      for (int i = 0; i < FM; ++i)
        #pragma unroll
        for (int j = 0; j < FN; ++j)
          acc[i][j] = __builtin_amdgcn_mfma_f32_16x16x32_bf16(af[i], bg[j], acc[i][j], 0, 0, 0);
    }
    __syncthreads();
  }

  const int brow = blockIdx.x * BM;
  const int bcol = blockIdx.y * BN;
  float* Cf = (float*)Cv;
  bf16*  Cb = (bf16*)Cv;
  #pragma unroll
  for (int i = 0; i < FM; ++i) {
    const int r0 = brow + wr + i * 16 + l16 * 4;
    #pragma unroll
    for (int j = 0; j < FN; ++j) {
      const int c = bcol + wc + j * 16 + l15;
      float bsv = 0.f;
      if constexpr (BIAS) bsv = bias[c];
      #pragma unroll
      for (int r = 0; r < 4; ++r) {
        float v = acc[i][j][r] * alpha + bsv;
        if constexpr (RESID) v += R[(size_t)(r0 + r) * ldc + c];
        if constexpr (RELU)  v = fmaxf(v, 0.f);
        const size_t off = (size_t)z * sC + (size_t)(r0 + r) * ldc + c;
        if constexpr (OUTBF) Cb[off] = (bf16)v; else Cf[off] = v;
      }
    }
  }
}

// ---------------------------------------------------------------------------
// Fused flash attention. Block = (64 q-rows, 1 head). 4 waves, 16 q-rows each.
// Q,K from QKV (t,3072): Q at h*64, K at 1024+h*64. V pre-transposed (Vt: row
// h*64+j, col t). Online softmax; P staged via XOR-swizzled LDS (256B rows).
// ---------------------------------------------------------------------------
__global__ __launch_bounds__(256) void flash_attn(
    const bf16* __restrict__ QKV, const bf16* __restrict__ Vt,
    bf16* __restrict__ XO)
{
  const int h   = blockIdx.y;
  const int t0  = blockIdx.x * 64;
  const int tid = threadIdx.x;
  const int lane = tid & 63;
  const int wv  = tid >> 6;
  const int l15 = lane & 15, l16 = lane >> 4;
  const int lr  = lane >> 3, lk = (lane & 7) * 8;

  __shared__ bf16 Ks[128 * 64];   // K tile: 128 keys x 64
  __shared__ bf16 Vs[64 * 128];   // V^T tile: 64 d x 128 keys
  __shared__ bf16 Ps[64 * 128];   // P tile: 64 q x 128 keys (swizzled)

  // Q fragments: rows wv*16 + l15, k = ks*32 + l16*8
  bf16x8 qf[2];
  #pragma unroll
  for (int ks = 0; ks < 2; ++ks)
    qf[ks] = *(const bf16x8*)(QKV + (size_t)(t0 + wv * 16 + l15) * 3072
                              + h * 64 + ks * 32 + l16 * 8);

  f32x4 o[4] = {};
  float m[4], lsum[4];
  #pragma unroll
  for (int r = 0; r < 4; ++r) { m[r] = -1e30f; lsum[r] = 0.f; }

  for (int kv = 0; kv < TD; kv += 128) {
    // stage K (128x64) and V^T (64x128)
    #pragma unroll
    for (int i = 0; i < 4; ++i) {
      const int sr = i * 4 + wv;
      gload_lds16(QKV + (size_t)(kv + sr * 8 + lr) * 3072 + 1024 + h * 64 + lk,
                  Ks + sr * 512);
    }
    #pragma unroll
    for (int i = 0; i < 4; ++i) {
      const int sr = i * 4 + wv;
      gload_lds16(Vt + (size_t)(h * 64 + sr * 4 + l16) * 1024 + kv + l15 * 8,
                  Vs + sr * 512);
    }
    __syncthreads();

    // S = (Q K^T) / 8
    f32x4 st[8] = {};
    #pragma unroll
    for (int ks = 0; ks < 2; ++ks) {
      #pragma unroll
      for (int j = 0; j < 8; ++j) {
        bf16x8 kf = *(const bf16x8*)(Ks + (j * 16 + l15) * 64 + ks * 32 + l16 * 8);
        st[j] = __builtin_amdgcn_mfma_f32_16x16x32_bf16(qf[ks], kf, st[j], 0, 0, 0);
      }
    }

    // online softmax; write P (bf16) to swizzled LDS
    #pragma unroll
    for (int r = 0; r < 4; ++r) {
      float mx = -1e30f;
      #pragma unroll
      for (int j = 0; j < 8; ++j) { st[j][r] *= 0.125f; mx = fmaxf(mx, st[j][r]); }
      #pragma unroll
      for (int off = 8; off; off >>= 1) mx = fmaxf(mx, __shfl_xor(mx, off, 64));
      const float nm = fmaxf(m[r], mx);
      const float sc = __expf(m[r] - nm);
      m[r] = nm;
      const int row = wv * 16 + l16 * 4 + r;
      char* prow = (char*)Ps + row * 256;
      float rs = 0.f;
      #pragma unroll
      for (int j = 0; j < 8; ++j) {
        float p = __expf(st[j][r] - nm);
        rs += p;
        *(bf16*)(prow + ((((j * 16 + l15) * 2)) ^ ((row & 7) << 4))) = (bf16)p;
      }
      #pragma unroll
      for (int off = 8; off; off >>= 1) rs += __shfl_xor(rs, off, 64);
      lsum[r] = lsum[r] * sc + rs;
      #pragma unroll
      for (int jo = 0; jo < 4; ++jo) o[jo][r] *= sc;
    }
    __syncthreads();

    // O += P V  (A = P rows q, k = key idx; B = Vs rows d, k = key idx)
    const int arow = wv * 16 + l15;
    #pragma unroll
    for (int ks2 = 0; ks2 < 4; ++ks2) {
      bf16x8 pa = *(const bf16x8*)((char*)Ps + arow * 256 +
                     ((ks2 * 64 + l16 * 16) ^ ((arow & 7) << 4)));
      #pragma unroll
      for (int jo = 0; jo < 4; ++jo) {
        bf16x8 vf = *(const bf16x8*)(Vs + (jo * 16 + l15) * 128 + ks2 * 32 + l16 * 8);
        o[jo] = __builtin_amdgcn_mfma_f32_16x16x32_bf16(pa, vf, o[jo], 0, 0, 0);
      }
    }
    __syncthreads();
  }

  #pragma unroll
  for (int r = 0; r < 4; ++r) {
    const float rinv = 1.0f / lsum[r];
    const int row = t0 + wv * 16 + l16 * 4 + r;
    #pragma unroll
    for (int jo = 0; jo < 4; ++jo)
      XO[(size_t)row * DD + h * 64 + jo * 16 + l15] = (bf16)(o[jo][r] * rinv);
  }
}

// ---------------------------------------------------------------------------
// Host launcher
// ---------------------------------------------------------------------------
extern "C" void kernel_launch(void* const* d_in, const int* in_sizes, int n_in,
                              void* d_out, int out_size, void* d_ws, size_t ws_size,
                              hipStream_t stream)
{
  const float* X     = (const float*)d_in[0];
  const float* Wemb  = (const float*)d_in[1];
  const float* pos   = (const float*)d_in[2];
  const float* WQ    = (const float*)d_in[3];
  const float* WK    = (const float*)d_in[4];
  const float* WV    = (const float*)d_in[5];
  const float* Wout  = (const float*)d_in[6];
  const float* ln1g  = (const float*)d_in[7];
  const float* ln1b  = (const float*)d_in[8];
  const float* ln2g  = (const float*)d_in[9];
  const float* ln2b  = (const float*)d_in[10];
  const float* w1    = (const float*)d_in[11];
  const float* b1    = (const float*)d_in[12];
  const float* w2    = (const float*)d_in[13];
  const float* b2    = (const float*)d_in[14];
  const float* lastg = (const float*)d_in[15];
  const float* lastb = (const float*)d_in[16];
  float* out = (float*)d_out;

  // ---- workspace carve-up (bytes; total ~92.3 MB) ----
  char* w = (char*)d_ws;
  float* XE    = (float*)(w + 0);          // 4 MB
  float* Yb    = (float*)(w + 4194304);    // 4 MB
  float* part  = (float*)(w + 8388608);    // 256 KB
  bf16*  LNbf  = (bf16*)(w + 8650752);     // 2 MB
  bf16*  QKVb  = (bf16*)(w + 10747904);    // 6 MB  (t, 3072)
  bf16*  Vt    = (bf16*)(w + 17039360);    // 2 MB  (h*64+j, t)
  bf16*  XO    = (bf16*)(w + 19136512);    // 2 MB
  bf16*  Hb    = (bf16*)(w + 21233664);    // 8 MB  (t, 4096)
  bf16*  QwAll = (bf16*)(w + 29622272);    // 12 MB (L*16 heads)x(64,1024)
  bf16*  KwAll = (bf16*)(w + 42205184);    // 12 MB
  bf16*  VwAll = (bf16*)(w + 54788096);    // 12 MB
  bf16*  WoAll = (bf16*)(w + 67371008);    // 12 MB (L)x(1024,1024) N,K
  bf16*  w1b   = (bf16*)(w + 79953920);    // 8 MB  per-layer (4096,1024)
  bf16*  w2b   = (bf16*)(w + 88342528);    // 8 MB  per-layer (1024,4096)

  // ---- pack QKV/Wout weights for ALL layers (once) ----
  transpose_cast<float><<<dim3(16, 1, NL * NH), 256, 0, stream>>>(
      WQ, HDIM, (long long)DD * HDIM, QwAll, DD, (long long)HDIM * DD);
  transpose_cast<float><<<dim3(16, 1, NL * NH), 256, 0, stream>>>(
      WK, HDIM, (long long)DD * HDIM, KwAll, DD, (long long)HDIM * DD);
  transpose_cast<float><<<dim3(16, 1, NL * NH), 256, 0, stream>>>(
      WV, HDIM, (long long)DD * HDIM, VwAll, DD, (long long)HDIM * DD);
  transpose_cast<float><<<dim3(16, 16, NL), 256, 0, stream>>>(
      Wout, DD, (long long)DD * DD, WoAll, DD, (long long)DD * DD);

  embed_kernel<<<TD, 256, 0, stream>>>(X, Wemb, pos, XE);

  for (int l = 0; l < NL; ++l) {
    const float* b1l = b1 + (size_t)l * FF;
    const float* b2l = b2 + (size_t)l * DD;

    // per-layer FFN weight casts (already (N,K))
    cast_bf4<<<FF * DD / 4 / 256, 256, 0, stream>>>(w1 + (size_t)l * FF * DD, w1b, FF * DD / 4);
    cast_bf4<<<FF * DD / 4 / 256, 256, 0, stream>>>(w2 + (size_t)l * DD * FF, w2b, FF * DD / 4);

    // ---- LN1 -> bf16 ----
    ln_stats_kernel<<<dim3(4, 32), 256, 0, stream>>>(XE, part);
    ln_apply_kernel<bf16><<<dim3(4, 32), 256, 0, stream>>>(
        XE, part, ln1g + l * DD, ln1b + l * DD, LNbf);

    // ---- QKV: z-batch over {Q,K,V} weight regions ----
    gemm_bf16<64, 128, 2, 2, true, false, false, false><<<dim3(16, 8, 3), 256, 0, stream>>>(
        LNbf, QwAll + (size_t)l * DD * DD, nullptr, nullptr, QKVb,
        DD, DD, DD, 3 * DD, 0LL, 6LL * 1024 * 1024, 1024LL, 1.0f);

    // ---- V transpose: Vt[h*64+j][t] = QKVb[t][2048+h*64+j] ----
    transpose_cast<bf16><<<dim3(16, 16, 1), 256, 0, stream>>>(
        QKVb + 2048, 3 * DD, 0LL, Vt, TD, 0LL);

    // ---- fused attention ----
    flash_attn<<<dim3(TD / 64, NH), 256, 0, stream>>>(QKVb, Vt, XO);

    // ---- Y = XE + XO @ Wout ----
    gemm_bf16<64, 64, 2, 2, false, false, true, false><<<dim3(16, 16, 1), 256, 0, stream>>>(
        XO, WoAll + (size_t)l * DD * DD, nullptr, XE, Yb,
        DD, DD, DD, DD, 0LL, 0LL, 0LL, 1.0f);

    // ---- LN2 -> bf16 ----
    ln_stats_kernel<<<dim3(4, 32), 256, 0, stream>>>(Yb, part);
    ln_apply_kernel<bf16><<<dim3(4, 32), 256, 0, stream>>>(
        Yb, part, ln2g + l * DD, ln2b + l * DD, LNbf);

    // ---- FFN1: H = relu(LN @ w1^T + b1) ----
    gemm_bf16<64, 128, 2, 2, true, true, false, true><<<dim3(16, 32, 1), 256, 0, stream>>>(
        LNbf, w1b, b1l, nullptr, Hb, DD, DD, DD, FF, 0LL, 0LL, 0LL, 1.0f);

    // ---- FFN2: XE = Yb + H @ w2^T + b2 ----
    gemm_bf16<64, 64, 2, 2, false, true, true, false><<<dim3(16, 16, 1), 256, 0, stream>>>(
        Hb, w2b, b2l, Yb, XE, FF, FF, FF, DD, 0LL, 0LL, 0LL, 1.0f);
  }

  // ---- final LN (fp32 out) ----
  ln_stats_kernel<<<dim3(4, 32), 256, 0, stream>>>(XE, part);
  ln_apply_kernel<float><<<dim3(4, 32), 256, 0, stream>>>(XE, part, lastg, lastb, out);
}

// Round 6
// 1416.941 us; speedup vs baseline: 6.3332x; 1.0336x over previous
//
#include <hip/hip_runtime.h>

// ============================================================================
// Transformer encoder forward — bf16 MFMA GEMMs (128x128 tiles + split-K),
// fused flash attention, fused splitK-reduce + residual + LN-stats.
// T=1024, D=1024, H=16, HD=64, DFF=4096, V=32000, L=6.
// ws: 108.2 MB base; 186.4 MB if ws_size allows all-layer weight cast.
// ============================================================================

#define TD   1024
#define DD   1024
#define NH   16
#define HDIM 64
#define FF   4096
#define VOC  32000
#define NL   6

typedef __bf16 bf16;
typedef __bf16 bf16x4 __attribute__((ext_vector_type(4)));
typedef __bf16 bf16x8 __attribute__((ext_vector_type(8)));
typedef float  f32x4  __attribute__((ext_vector_type(4)));

__device__ __forceinline__ void gload_lds16(const void* g, void* l) {
  __builtin_amdgcn_global_load_lds(
      (__attribute__((address_space(1))) void*)(g),
      (__attribute__((address_space(3))) void*)(l), 16, 0, 0);
}

// ---------------------------------------------------------------------------
// Embedding: one-hot gather + positional add. One block per t.
// ---------------------------------------------------------------------------
__global__ __launch_bounds__(256) void embed_kernel(
    const float* __restrict__ X, const float* __restrict__ Wemb,
    const float* __restrict__ pos, float* __restrict__ Xe)
{
  const int t = blockIdx.x;
  __shared__ int sidx;
  const float4* row = (const float4*)(X + (size_t)t * VOC);
  for (int i = threadIdx.x; i < VOC / 4; i += 256) {
    float4 v = row[i];
    if (v.x > 0.5f) sidx = 4 * i;
    if (v.y > 0.5f) sidx = 4 * i + 1;
    if (v.z > 0.5f) sidx = 4 * i + 2;
    if (v.w > 0.5f) sidx = 4 * i + 3;
  }
  __syncthreads();
  const float4* w = (const float4*)(Wemb + (size_t)sidx * DD);
  const float4* p = (const float4*)(pos + (size_t)t * DD);
  float4* o = (float4*)(Xe + (size_t)t * DD);
  const int d = threadIdx.x;
  float4 a = w[d], b = p[d];
  o[d] = make_float4(a.x + b.x, a.y + b.y, a.z + b.z, a.w + b.w);
}

// ---------------------------------------------------------------------------
// LN column stats (sum, sumsq) over 32-row chunks. part[col*64+tc], [..+32+tc]
// ---------------------------------------------------------------------------
__global__ __launch_bounds__(256) void ln_stats_kernel(
    const float* __restrict__ Y, float* __restrict__ part)
{
  const int col = blockIdx.x * 256 + threadIdx.x;
  const int tc  = blockIdx.y;
  const float* p = Y + (size_t)(tc * 32) * DD + col;
  float s = 0.f, s2 = 0.f;
  #pragma unroll 8
  for (int t = 0; t < 32; ++t) {
    float v = p[(size_t)t * DD];
    s += v;
    s2 = fmaf(v, v, s2);
  }
  part[col * 64 + tc]      = s;
  part[col * 64 + 32 + tc] = s2;
}

template<typename OutT>
__global__ __launch_bounds__(256) void ln_apply_kernel(
    const float* __restrict__ Y, const float* __restrict__ part,
    const float* __restrict__ g, const float* __restrict__ b,
    OutT* __restrict__ out)
{
  const int col = blockIdx.x * 256 + threadIdx.x;
  const int tc  = blockIdx.y;
  float s = 0.f, s2 = 0.f;
  const float* pp = part + col * 64;
  #pragma unroll
  for (int i = 0; i < 32; ++i) { s += pp[i]; s2 += pp[32 + i]; }
  const float mu  = s * (1.0f / TD);
  const float var = (s2 - (float)TD * mu * mu) * (1.0f / (TD - 1));
  const float inv = 1.0f / sqrtf(var);
  const float gi  = g[col] * inv;
  const float bb  = b[col];
  const float* yp = Y   + (size_t)(tc * 32) * DD + col;
  OutT*        op = out + (size_t)(tc * 32) * DD + col;
  #pragma unroll 8
  for (int t = 0; t < 32; ++t)
    op[(size_t)t * DD] = (OutT)fmaf(gi, yp[(size_t)t * DD] - mu, bb);
}

// ---------------------------------------------------------------------------
// Split-K reduce: out = resid + sum_{s<4} SK[s] (+bias). Also LN column stats.
// Grid (4, 32) x 256 threads, same tiling as ln_stats.
// ---------------------------------------------------------------------------
template<bool BIAS>
__global__ __launch_bounds__(256) void reduce4_stats(
    const float* __restrict__ SK, const float* __restrict__ bias,
    const float* __restrict__ resid, float* __restrict__ out,
    float* __restrict__ part)
{
  const int col = blockIdx.x * 256 + threadIdx.x;
  const int tc  = blockIdx.y;
  const float bb = BIAS ? bias[col] : 0.f;
  float s = 0.f, s2 = 0.f;
  #pragma unroll 4
  for (int t = 0; t < 32; ++t) {
    const size_t idx = (size_t)(tc * 32 + t) * DD + col;
    float v = resid[idx] + bb
            + SK[idx] + SK[idx + (size_t)TD * DD]
            + SK[idx + 2 * (size_t)TD * DD] + SK[idx + 3 * (size_t)TD * DD];
    out[idx] = v;
    s += v;
    s2 = fmaf(v, v, s2);
  }
  part[col * 64 + tc]      = s;
  part[col * 64 + 32 + tc] = s2;
}

// ---------------------------------------------------------------------------
// 64x64 tile transpose + cast to bf16.
// ---------------------------------------------------------------------------
template<typename ST>
__global__ __launch_bounds__(256) void transpose_cast(
    const ST* __restrict__ src, int lds_, long long sZ,
    bf16* __restrict__ dst, int ldd, long long dZ)
{
  __shared__ ST tile[64][65];
  src += (size_t)blockIdx.z * sZ + (size_t)(blockIdx.x * 64) * lds_ + blockIdx.y * 64;
  dst += (size_t)blockIdx.z * dZ + (size_t)(blockIdx.y * 64) * ldd + blockIdx.x * 64;
  const int tid = threadIdx.x;
  #pragma unroll
  for (int k = 0; k < 16; ++k) {
    const int idx = tid + k * 256;
    const int r = idx >> 6, c = idx & 63;
    tile[r][c] = src[(size_t)r * lds_ + c];
  }
  __syncthreads();
  #pragma unroll
  for (int k = 0; k < 16; ++k) {
    const int idx = tid + k * 256;
    const int r = idx >> 6, c = idx & 63;
    dst[(size_t)r * ldd + c] = (bf16)(float)tile[c][r];
  }
}

__global__ __launch_bounds__(256) void cast_bf4(
    const float* __restrict__ s, bf16* __restrict__ d, int n4)
{
  const int i = blockIdx.x * 256 + threadIdx.x;
  if (i < n4) {
    float4 v = ((const float4*)s)[i];
    bf16x4 o = { (bf16)v.x, (bf16)v.y, (bf16)v.z, (bf16)v.w };
    ((bf16x4*)d)[i] = o;
  }
}

// ---------------------------------------------------------------------------
// bf16 MFMA GEMM (m97 structure): C = alpha*A(MxK)*B(NxK)^T [+bias][+R][relu]
// Split-K usage: z-stride sA=sB=Ks shifts the K window; sC=T*D -> fp32 partials.
// ---------------------------------------------------------------------------
template<int BM, int BN, int WGM, int WGN, bool OUTBF, bool BIAS, bool RESID, bool RELU>
__global__ __launch_bounds__(256) void gemm_bf16(
    const bf16* __restrict__ A, const bf16* __restrict__ B,
    const float* __restrict__ bias, const float* __restrict__ R,
    void* __restrict__ Cv,
    int K, int lda, int ldb, int ldc,
    long long sA, long long sB, long long sC, float alpha)
{
  constexpr int FM = BM / WGM / 16;
  constexpr int FN = BN / WGN / 16;
  __shared__ bf16 sm[(BM + BN) * 64];
  bf16* As = sm;
  bf16* Bs = sm + BM * 64;

  const int z = blockIdx.z;
  A += (size_t)z * sA + (size_t)(blockIdx.x * BM) * lda;
  B += (size_t)z * sB + (size_t)(blockIdx.y * BN) * ldb;

  const int tid  = threadIdx.x;
  const int lane = tid & 63;
  const int wv   = tid >> 6;
  const int lr   = lane >> 3;
  const int lk   = (lane & 7) * 8;
  const int wr   = (wv / WGN) * FM * 16;
  const int wc   = (wv % WGN) * FN * 16;
  const int l15  = lane & 15;
  const int l16  = lane >> 4;

  f32x4 acc[FM][FN] = {};

  for (int k0 = 0; k0 < K; k0 += 64) {
    #pragma unroll
    for (int s8 = 0; s8 < BM / 32; ++s8) {
      const int s = s8 * 4 + wv;
      gload_lds16(A + (size_t)(s * 8 + lr) * lda + (k0 + lk), As + s * 512);
    }
    #pragma unroll
    for (int s8 = 0; s8 < BN / 32; ++s8) {
      const int s = s8 * 4 + wv;
      gload_lds16(B + (size_t)(s * 8 + lr) * ldb + (k0 + lk), Bs + s * 512);
    }
    __syncthreads();

    #pragma unroll
    for (int ks = 0; ks < 2; ++ks) {
      const int ko = ks * 32 + l16 * 8;
      bf16x8 af[FM], bg[FN];
      #pragma unroll
      for (int i = 0; i < FM; ++i)
        af[i] = *(const bf16x8*)(As + (wr + i * 16 + l15) * 64 + ko);
      #pragma unroll
      for (int j = 0; j < FN; ++j)
        bg[j] = *(const bf16x8*)(Bs + (wc + j * 16 + l15) * 64 + ko);
      #pragma unroll
      for (int i = 0; i < FM; ++i)
        #pragma unroll
        for (int j = 0; j < FN; ++j)
          acc[i][j] = __builtin_amdgcn_mfma_f32_16x16x32_bf16(af[i], bg[j], acc[i][j], 0, 0, 0);
    }
    __syncthreads();
  }

  const int brow = blockIdx.x * BM;
  const int bcol = blockIdx.y * BN;
  float* Cf = (float*)Cv;
  bf16*  Cb = (bf16*)Cv;
  #pragma unroll
  for (int i = 0; i < FM; ++i) {
    const int r0 = brow + wr + i * 16 + l16 * 4;
    #pragma unroll
    for (int j = 0; j < FN; ++j) {
      const int c = bcol + wc + j * 16 + l15;
      float bsv = 0.f;
      if constexpr (BIAS) bsv = bias[c];
      #pragma unroll
      for (int r = 0; r < 4; ++r) {
        float v = acc[i][j][r] * alpha + bsv;
        if constexpr (RESID) v += R[(size_t)(r0 + r) * ldc + c];
        if constexpr (RELU)  v = fmaxf(v, 0.f);
        const size_t off = (size_t)z * sC + (size_t)(r0 + r) * ldc + c;
        if constexpr (OUTBF) Cb[off] = (bf16)v; else Cf[off] = v;
      }
    }
  }
}

// ---------------------------------------------------------------------------
// Fused flash attention (unchanged from round 3/5 — verified).
// ---------------------------------------------------------------------------
__global__ __launch_bounds__(256) void flash_attn(
    const bf16* __restrict__ QKV, const bf16* __restrict__ Vt,
    bf16* __restrict__ XO)
{
  const int h   = blockIdx.y;
  const int t0  = blockIdx.x * 64;
  const int tid = threadIdx.x;
  const int lane = tid & 63;
  const int wv  = tid >> 6;
  const int l15 = lane & 15, l16 = lane >> 4;
  const int lr  = lane >> 3, lk = (lane & 7) * 8;

  __shared__ bf16 Ks[128 * 64];
  __shared__ bf16 Vs[64 * 128];
  __shared__ bf16 Ps[64 * 128];

  bf16x8 qf[2];
  #pragma unroll
  for (int ks = 0; ks < 2; ++ks)
    qf[ks] = *(const bf16x8*)(QKV + (size_t)(t0 + wv * 16 + l15) * 3072
                              + h * 64 + ks * 32 + l16 * 8);

  f32x4 o[4] = {};
  float m[4], lsum[4];
  #pragma unroll
  for (int r = 0; r < 4; ++r) { m[r] = -1e30f; lsum[r] = 0.f; }

  for (int kv = 0; kv < TD; kv += 128) {
    #pragma unroll
    for (int i = 0; i < 4; ++i) {
      const int sr = i * 4 + wv;
      gload_lds16(QKV + (size_t)(kv + sr * 8 + lr) * 3072 + 1024 + h * 64 + lk,
                  Ks + sr * 512);
    }
    #pragma unroll
    for (int i = 0; i < 4; ++i) {
      const int sr = i * 4 + wv;
      gload_lds16(Vt + (size_t)(h * 64 + sr * 4 + l16) * 1024 + kv + l15 * 8,
                  Vs + sr * 512);
    }
    __syncthreads();

    f32x4 st[8] = {};
    #pragma unroll
    for (int ks = 0; ks < 2; ++ks) {
      #pragma unroll
      for (int j = 0; j < 8; ++j) {
        bf16x8 kf = *(const bf16x8*)(Ks + (j * 16 + l15) * 64 + ks * 32 + l16 * 8);
        st[j] = __builtin_amdgcn_mfma_f32_16x16x32_bf16(qf[ks], kf, st[j], 0, 0, 0);
      }
    }

    #pragma unroll
    for (int r = 0; r < 4; ++r) {
      float mx = -1e30f;
      #pragma unroll
      for (int j = 0; j < 8; ++j) { st[j][r] *= 0.125f; mx = fmaxf(mx, st[j][r]); }
      #pragma unroll
      for (int off = 8; off; off >>= 1) mx = fmaxf(mx, __shfl_xor(mx, off, 64));
      const float nm = fmaxf(m[r], mx);
      const float sc = __expf(m[r] - nm);
      m[r] = nm;
      const int row = wv * 16 + l16 * 4 + r;
      char* prow = (char*)Ps + row * 256;
      float rs = 0.f;
      #pragma unroll
      for (int j = 0; j < 8; ++j) {
        float p = __expf(st[j][r] - nm);
        rs += p;
        *(bf16*)(prow + ((((j * 16 + l15) * 2)) ^ ((row & 7) << 4))) = (bf16)p;
      }
      #pragma unroll
      for (int off = 8; off; off >>= 1) rs += __shfl_xor(rs, off, 64);
      lsum[r] = lsum[r] * sc + rs;
      #pragma unroll
      for (int jo = 0; jo < 4; ++jo) o[jo][r] *= sc;
    }
    __syncthreads();

    const int arow = wv * 16 + l15;
    #pragma unroll
    for (int ks2 = 0; ks2 < 4; ++ks2) {
      bf16x8 pa = *(const bf16x8*)((char*)Ps + arow * 256 +
                     ((ks2 * 64 + l16 * 16) ^ ((arow & 7) << 4)));
      #pragma unroll
      for (int jo = 0; jo < 4; ++jo) {
        bf16x8 vf = *(const bf16x8*)(Vs + (jo * 16 + l15) * 128 + ks2 * 32 + l16 * 8);
        o[jo] = __builtin_amdgcn_mfma_f32_16x16x32_bf16(pa, vf, o[jo], 0, 0, 0);
      }
    }
    __syncthreads();
  }

  #pragma unroll
  for (int r = 0; r < 4; ++r) {
    const float rinv = 1.0f / lsum[r];
    const int row = t0 + wv * 16 + l16 * 4 + r;
    #pragma unroll
    for (int jo = 0; jo < 4; ++jo)
      XO[(size_t)row * DD + h * 64 + jo * 16 + l15] = (bf16)(o[jo][r] * rinv);
  }
}

// ---------------------------------------------------------------------------
// Host launcher
// ---------------------------------------------------------------------------
extern "C" void kernel_launch(void* const* d_in, const int* in_sizes, int n_in,
                              void* d_out, int out_size, void* d_ws, size_t ws_size,
                              hipStream_t stream)
{
  const float* X     = (const float*)d_in[0];
  const float* Wemb  = (const float*)d_in[1];
  const float* pos   = (const float*)d_in[2];
  const float* WQ    = (const float*)d_in[3];
  const float* WK    = (const float*)d_in[4];
  const float* WV    = (const float*)d_in[5];
  const float* Wout  = (const float*)d_in[6];
  const float* ln1g  = (const float*)d_in[7];
  const float* ln1b  = (const float*)d_in[8];
  const float* ln2g  = (const float*)d_in[9];
  const float* ln2b  = (const float*)d_in[10];
  const float* w1    = (const float*)d_in[11];
  const float* b1    = (const float*)d_in[12];
  const float* w2    = (const float*)d_in[13];
  const float* b2    = (const float*)d_in[14];
  const float* lastg = (const float*)d_in[15];
  const float* lastb = (const float*)d_in[16];
  float* out = (float*)d_out;

  // ---- workspace carve-up (bytes) ----
  char* w = (char*)d_ws;
  float* XE    = (float*)(w + 0);          // 4 MB fp32 residual
  float* Yb    = (float*)(w + 4194304);    // 4 MB fp32 post-attn residual
  float* part  = (float*)(w + 8388608);    // 256 KB LN partials
  bf16*  LNbf  = (bf16*)(w + 8650752);     // 2 MB LN out (bf16)
  bf16*  QKVb  = (bf16*)(w + 10747904);    // 6 MB QKV acts (t,3072)
  bf16*  Vt    = (bf16*)(w + 17039360);    // 2 MB V^T (h*64+j, t)
  bf16*  XO    = (bf16*)(w + 19136512);    // 2 MB attn out
  bf16*  Hb    = (bf16*)(w + 21233664);    // 8 MB ffn hidden (t,4096)
  float* SK    = (float*)(w + 29622272);   // 16 MB split-K partials (4 x T*D)
  bf16*  QwAll = (bf16*)(w + 46399488);    // 12 MB
  bf16*  KwAll = (bf16*)(w + 58982400);    // 12 MB
  bf16*  VwAll = (bf16*)(w + 71565312);    // 12 MB
  bf16*  WoAll = (bf16*)(w + 84148224);    // 12 MB  -> ends 96,731,136
  // w1/w2 bf16: per-layer (8+8 MB, end 113.5 MB) or all-layer (48+48 MB, end 195.4 MB)
  const bool allW = ws_size >= 195428352ULL;
  bf16* w1b = (bf16*)(w + 96731136);
  bf16* w2b = allW ? (bf16*)(w + 147062784) : (bf16*)(w + 105119744);

  // ---- pack QKV/Wout weights for ALL layers (once) ----
  transpose_cast<float><<<dim3(16, 1, NL * NH), 256, 0, stream>>>(
      WQ, HDIM, (long long)DD * HDIM, QwAll, DD, (long long)HDIM * DD);
  transpose_cast<float><<<dim3(16, 1, NL * NH), 256, 0, stream>>>(
      WK, HDIM, (long long)DD * HDIM, KwAll, DD, (long long)HDIM * DD);
  transpose_cast<float><<<dim3(16, 1, NL * NH), 256, 0, stream>>>(
      WV, HDIM, (long long)DD * HDIM, VwAll, DD, (long long)HDIM * DD);
  transpose_cast<float><<<dim3(16, 16, NL), 256, 0, stream>>>(
      Wout, DD, (long long)DD * DD, WoAll, DD, (long long)DD * DD);
  if (allW) {
    cast_bf4<<<NL * FF * DD / 4 / 256, 256, 0, stream>>>(w1, w1b, NL * FF * DD / 4);
    cast_bf4<<<NL * FF * DD / 4 / 256, 256, 0, stream>>>(w2, w2b, NL * FF * DD / 4);
  }

  embed_kernel<<<TD, 256, 0, stream>>>(X, Wemb, pos, XE);
  ln_stats_kernel<<<dim3(4, 32), 256, 0, stream>>>(XE, part);  // stats for L0 LN1

  for (int l = 0; l < NL; ++l) {
    const float* b1l = b1 + (size_t)l * FF;
    const float* b2l = b2 + (size_t)l * DD;
    bf16* w1bl = allW ? w1b + (size_t)l * FF * DD : w1b;
    bf16* w2bl = allW ? w2b + (size_t)l * DD * FF : w2b;
    if (!allW) {
      cast_bf4<<<FF * DD / 4 / 256, 256, 0, stream>>>(w1 + (size_t)l * FF * DD, w1bl, FF * DD / 4);
      cast_bf4<<<FF * DD / 4 / 256, 256, 0, stream>>>(w2 + (size_t)l * DD * FF, w2bl, FF * DD / 4);
    }

    // ---- LN1 apply (stats from prev FFN2-reduce / embed stats) ----
    ln_apply_kernel<bf16><<<dim3(4, 32), 256, 0, stream>>>(
        XE, part, ln1g + l * DD, ln1b + l * DD, LNbf);

    // ---- QKV: 128x128 tiles, z-batch over {Q,K,V} ----
    gemm_bf16<128, 128, 2, 2, true, false, false, false><<<dim3(8, 8, 3), 256, 0, stream>>>(
        LNbf, QwAll + (size_t)l * DD * DD, nullptr, nullptr, QKVb,
        DD, DD, DD, 3 * DD, 0LL, 6LL * 1024 * 1024, 1024LL, 1.0f);

    // ---- V transpose ----
    transpose_cast<bf16><<<dim3(16, 16, 1), 256, 0, stream>>>(
        QKVb + 2048, 3 * DD, 0LL, Vt, TD, 0LL);

    // ---- fused flash attention ----
    flash_attn<<<dim3(TD / 64, NH), 256, 0, stream>>>(QKVb, Vt, XO);

    // ---- Wout: split-K=4 (K window 256 per z) -> SK partials ----
    gemm_bf16<128, 128, 2, 2, false, false, false, false><<<dim3(8, 8, 4), 256, 0, stream>>>(
        XO, WoAll + (size_t)l * DD * DD, nullptr, nullptr, SK,
        256, DD, DD, DD, 256LL, 256LL, (long long)TD * DD, 1.0f);
    // Yb = XE + sum(SK); also LN2 stats
    reduce4_stats<false><<<dim3(4, 32), 256, 0, stream>>>(SK, nullptr, XE, Yb, part);

    // ---- LN2 apply ----
    ln_apply_kernel<bf16><<<dim3(4, 32), 256, 0, stream>>>(
        Yb, part, ln2g + l * DD, ln2b + l * DD, LNbf);

    // ---- FFN1: 128x128, bias+relu ----
    gemm_bf16<128, 128, 2, 2, true, true, false, true><<<dim3(8, 32, 1), 256, 0, stream>>>(
        LNbf, w1bl, b1l, nullptr, Hb, DD, DD, DD, FF, 0LL, 0LL, 0LL, 1.0f);

    // ---- FFN2: split-K=4 (K window 1024 per z) -> SK partials ----
    gemm_bf16<128, 128, 2, 2, false, false, false, false><<<dim3(8, 8, 4), 256, 0, stream>>>(
        Hb, w2bl, nullptr, nullptr, SK,
        1024, FF, FF, DD, 1024LL, 1024LL, (long long)TD * DD, 1.0f);
    // XE = Yb + sum(SK) + b2; also next LN1 / final LN stats
    reduce4_stats<true><<<dim3(4, 32), 256, 0, stream>>>(SK, b2l, Yb, XE, part);
  }

  // ---- final LN (stats already in part from last FFN2-reduce) ----
  ln_apply_kernel<float><<<dim3(4, 32), 256, 0, stream>>>(XE, part, lastg, lastb, out);
}